// Round 1
// baseline (2132.414 us; speedup 1.0000x reference)
//
#include <hip/hip_runtime.h>
#include <math.h>

// Problem constants (verified against setup_inputs): N=50000, IN=128, H=4, C=64
#define HH 4
#define CC 64
#define HC 256

static constexpr float NEG_SLOPE = 0.2f;
static constexpr float LN_EPS = 1e-5f;

// ---------------- GEMM: C[M,Ncol] = A[M,K] @ B[K,Ncol] (+ bias) ----------------
// 64x64 tile, BK=16, 256 threads, 4x4 per thread. fp32 (no fp32 MFMA on CDNA4).
__global__ __launch_bounds__(256) void gemm64(
    const float* __restrict__ A, const float* __restrict__ B,
    const float* __restrict__ bias, float* __restrict__ Cmat,
    int M, int Ncol, int K) {
  __shared__ float As[16][65];   // [k][m], +1 pad
  __shared__ float Bs[16][68];   // [k][n], +4 pad (keeps float4 LDS stores aligned)
  const int tid = threadIdx.x;
  const int tx = tid & 15, ty = tid >> 4;
  const int row0 = blockIdx.x * 64;
  const int col0 = blockIdx.y * 64;
  const int ar = tid >> 2;          // A row in tile 0..63
  const int ak = (tid & 3) * 4;     // A k offset 0,4,8,12
  const int bk = tid >> 4;          // B k in tile 0..15
  const int bn = (tid & 15) * 4;    // B col offset 0..60

  float acc[4][4] = {};
  for (int k0 = 0; k0 < K; k0 += 16) {
    float4 av = make_float4(0.f, 0.f, 0.f, 0.f);
    const int arow = row0 + ar;
    if (arow < M) av = *(const float4*)(A + (size_t)arow * K + k0 + ak);
    As[ak + 0][ar] = av.x; As[ak + 1][ar] = av.y;
    As[ak + 2][ar] = av.z; As[ak + 3][ar] = av.w;
    const float4 bv = *(const float4*)(B + (size_t)(k0 + bk) * Ncol + col0 + bn);
    *(float4*)(&Bs[bk][bn]) = bv;
    __syncthreads();
#pragma unroll
    for (int kk = 0; kk < 16; ++kk) {
      const float a0 = As[kk][ty * 4 + 0], a1 = As[kk][ty * 4 + 1];
      const float a2 = As[kk][ty * 4 + 2], a3 = As[kk][ty * 4 + 3];
      const float b0 = Bs[kk][tx * 4 + 0], b1 = Bs[kk][tx * 4 + 1];
      const float b2 = Bs[kk][tx * 4 + 2], b3 = Bs[kk][tx * 4 + 3];
      acc[0][0] += a0 * b0; acc[0][1] += a0 * b1; acc[0][2] += a0 * b2; acc[0][3] += a0 * b3;
      acc[1][0] += a1 * b0; acc[1][1] += a1 * b1; acc[1][2] += a1 * b2; acc[1][3] += a1 * b3;
      acc[2][0] += a2 * b0; acc[2][1] += a2 * b1; acc[2][2] += a2 * b2; acc[2][3] += a2 * b3;
      acc[3][0] += a3 * b0; acc[3][1] += a3 * b1; acc[3][2] += a3 * b2; acc[3][3] += a3 * b3;
    }
    __syncthreads();
  }
#pragma unroll
  for (int i = 0; i < 4; ++i) {
    const int r = row0 + ty * 4 + i;
    if (r < M) {
      const int ccol = col0 + tx * 4;
      float4 v = make_float4(acc[i][0], acc[i][1], acc[i][2], acc[i][3]);
      if (bias) {
        v.x += bias[ccol + 0]; v.y += bias[ccol + 1];
        v.z += bias[ccol + 2]; v.w += bias[ccol + 3];
      }
      *(float4*)(Cmat + (size_t)r * Ncol + ccol) = v;
    }
  }
}

// ---------------- per-node attention coefficients: alpha = sum_c h*att ----------------
// one block per node, 256 threads; each wave (64 lanes) = one head.
__global__ __launch_bounds__(256) void alpha_kernel(
    const float* __restrict__ h, const float* __restrict__ att_src,
    const float* __restrict__ att_dst,
    float* __restrict__ as_, float* __restrict__ ad_) {
  const int n = blockIdx.x;
  const int i = threadIdx.x;  // 0..255 = head*64 + c
  const float v = h[(size_t)n * HC + i];
  float ps = v * att_src[i];
  float pd = v * att_dst[i];
#pragma unroll
  for (int off = 32; off > 0; off >>= 1) {
    ps += __shfl_down(ps, off);
    pd += __shfl_down(pd, off);
  }
  if ((i & 63) == 0) {
    const int hh = i >> 6;
    as_[n * HH + hh] = ps;
    ad_[n * HH + hh] = pd;
  }
}

// ---------------- edge pass 1: softmax denominators (no max-shift; e is O(1)) ----------------
__global__ __launch_bounds__(256) void edge_denom(
    const int* __restrict__ srcs, const int* __restrict__ dsts,
    const float* __restrict__ as_, const float* __restrict__ ad_,
    float* __restrict__ ssum, int E, int N) {
  const int e = blockIdx.x * 256 + threadIdx.x;
  if (e >= E + N) return;
  int s, d;
  if (e < E) { s = srcs[e]; d = dsts[e]; }
  else       { s = e - E; d = s; }
  const float4 a4 = *(const float4*)(as_ + (size_t)s * 4);
  const float4 d4 = *(const float4*)(ad_ + (size_t)d * 4);
  float v;
  v = a4.x + d4.x; v = v > 0.f ? v : NEG_SLOPE * v; atomicAdd(&ssum[d * 4 + 0], expf(v));
  v = a4.y + d4.y; v = v > 0.f ? v : NEG_SLOPE * v; atomicAdd(&ssum[d * 4 + 1], expf(v));
  v = a4.z + d4.z; v = v > 0.f ? v : NEG_SLOPE * v; atomicAdd(&ssum[d * 4 + 2], expf(v));
  v = a4.w + d4.w; v = v > 0.f ? v : NEG_SLOPE * v; atomicAdd(&ssum[d * 4 + 3], expf(v));
}

// ---------------- edge pass 2: weighted scatter-aggregate ----------------
// one block (256 thr) per edge: thread = (head, channel); coalesced 1KB gather + 1KB atomic scatter
__global__ __launch_bounds__(256) void edge_aggregate(
    const int* __restrict__ srcs, const int* __restrict__ dsts,
    const float* __restrict__ as_, const float* __restrict__ ad_,
    const float* __restrict__ ssum, const float* __restrict__ hlin,
    float* __restrict__ agg, int E, int N) {
  const int e = blockIdx.x;
  const int hh = threadIdx.x >> 6;
  const int c = threadIdx.x & 63;
  int s, d;
  if (e < E) { s = srcs[e]; d = dsts[e]; }
  else       { s = e - E; d = s; }
  float v = as_[s * 4 + hh] + ad_[d * 4 + hh];
  v = v > 0.f ? v : NEG_SLOPE * v;
  const float w = expf(v) / ssum[d * 4 + hh];
  const float msg = hlin[(size_t)s * HC + hh * 64 + c] * w;
  atomicAdd(&agg[(size_t)d * HC + hh * 64 + c], msg);
}

// ---------------- +bias1, LayerNorm(g1,b1), ELU — in place on [N,256] ----------------
__global__ __launch_bounds__(256) void ln_elu1(
    float* __restrict__ buf, const float* __restrict__ bias1,
    const float* __restrict__ g1, const float* __restrict__ b1) {
  const int n = blockIdx.x;
  const int i = threadIdx.x;
  const float v = buf[(size_t)n * HC + i] + bias1[i];
  float s1 = v, s2 = v * v;
#pragma unroll
  for (int off = 32; off > 0; off >>= 1) {
    s1 += __shfl_down(s1, off);
    s2 += __shfl_down(s2, off);
  }
  __shared__ float ws1[4], ws2[4];
  if ((i & 63) == 0) { ws1[i >> 6] = s1; ws2[i >> 6] = s2; }
  __syncthreads();
  const float tot1 = ws1[0] + ws1[1] + ws1[2] + ws1[3];
  const float tot2 = ws2[0] + ws2[1] + ws2[2] + ws2[3];
  const float mu = tot1 * (1.0f / HC);
  const float var = tot2 * (1.0f / HC) - mu * mu;
  float y = (v - mu) * rsqrtf(var + LN_EPS) * g1[i] + b1[i];
  y = y > 0.f ? y : expm1f(y);
  buf[(size_t)n * HC + i] = y;
}

// ---------------- head-mean + bias2 + LayerNorm + residual + ELU -> out [N,64] ----------------
__global__ __launch_bounds__(64) void final_kernel(
    const float* __restrict__ agg2, const float* __restrict__ ident,
    const float* __restrict__ bias2, const float* __restrict__ g2,
    const float* __restrict__ b2, float* __restrict__ out) {
  const int n = blockIdx.x;
  const int c = threadIdx.x;  // 0..63, one wave
  const size_t base = (size_t)n * HC;
  float v = 0.25f * (agg2[base + c] + agg2[base + 64 + c] +
                     agg2[base + 128 + c] + agg2[base + 192 + c]) + bias2[c];
  float s1 = v, s2 = v * v;
#pragma unroll
  for (int off = 32; off > 0; off >>= 1) {
    s1 += __shfl_down(s1, off);
    s2 += __shfl_down(s2, off);
  }
  s1 = __shfl(s1, 0);
  s2 = __shfl(s2, 0);
  const float mu = s1 * (1.0f / 64.0f);
  const float var = s2 * (1.0f / 64.0f) - mu * mu;
  float y = (v - mu) * rsqrtf(var + LN_EPS) * g2[c] + b2[c];
  y += ident[(size_t)n * 64 + c];
  out[(size_t)n * 64 + c] = y > 0.f ? y : expm1f(y);
}

extern "C" void kernel_launch(void* const* d_in, const int* in_sizes, int n_in,
                              void* d_out, int out_size, void* d_ws, size_t ws_size,
                              hipStream_t stream) {
  const float* x        = (const float*)d_in[0];
  const int*   ei       = (const int*)d_in[1];
  const float* W1       = (const float*)d_in[2];
  const float* att_src1 = (const float*)d_in[3];
  const float* att_dst1 = (const float*)d_in[4];
  const float* bias1    = (const float*)d_in[5];
  const float* g1       = (const float*)d_in[6];
  const float* b1       = (const float*)d_in[7];
  const float* W2       = (const float*)d_in[8];
  const float* att_src2 = (const float*)d_in[9];
  const float* att_dst2 = (const float*)d_in[10];
  const float* bias2    = (const float*)d_in[11];
  const float* g2       = (const float*)d_in[12];
  const float* b2       = (const float*)d_in[13];
  const float* Wres     = (const float*)d_in[14];
  const float* bres     = (const float*)d_in[15];

  const int N = in_sizes[0] / 128;   // 50000
  const int E = in_sizes[1] / 2;     // 800000
  const int IN = 128;
  const int Etot = E + N;            // with self loops

  const int* srcs = ei;
  const int* dsts = ei + E;

  // workspace layout (floats): ident[N*64] | bufA[N*256] | bufB[N*256] |
  //   as1[N*4] ad1[N*4] as2[N*4] ad2[N*4] ssum[N*4]   -> ~119 MB total
  float* ws    = (float*)d_ws;
  float* ident = ws;
  float* bufA  = ident + (size_t)N * 64;
  float* bufB  = bufA + (size_t)N * HC;
  float* as1   = bufB + (size_t)N * HC;
  float* ad1   = as1 + (size_t)N * HH;
  float* as2   = ad1 + (size_t)N * HH;
  float* ad2   = as2 + (size_t)N * HH;
  float* ssum  = ad2 + (size_t)N * HH;

  const int mblocks = (N + 63) / 64;
  dim3 blk(256);

  // residual projection: ident = x @ Wres + bres   [N,64]
  gemm64<<<dim3(mblocks, 1), blk, 0, stream>>>(x, Wres, bres, ident, N, 64, IN);

  // ---- GAT layer 1 ----
  gemm64<<<dim3(mblocks, 4), blk, 0, stream>>>(x, W1, nullptr, bufA, N, HC, IN);
  alpha_kernel<<<N, blk, 0, stream>>>(bufA, att_src1, att_dst1, as1, ad1);
  hipMemsetAsync(ssum, 0, (size_t)N * HH * sizeof(float), stream);
  hipMemsetAsync(bufB, 0, (size_t)N * HC * sizeof(float), stream);
  edge_denom<<<(Etot + 255) / 256, blk, 0, stream>>>(srcs, dsts, as1, ad1, ssum, E, N);
  edge_aggregate<<<Etot, blk, 0, stream>>>(srcs, dsts, as1, ad1, ssum, bufA, bufB, E, N);
  ln_elu1<<<N, blk, 0, stream>>>(bufB, bias1, g1, b1);   // bufB now holds h1

  // ---- GAT layer 2 ----
  gemm64<<<dim3(mblocks, 4), blk, 0, stream>>>(bufB, W2, nullptr, bufA, N, HC, HC);
  alpha_kernel<<<N, blk, 0, stream>>>(bufA, att_src2, att_dst2, as2, ad2);
  hipMemsetAsync(ssum, 0, (size_t)N * HH * sizeof(float), stream);
  edge_denom<<<(Etot + 255) / 256, blk, 0, stream>>>(srcs, dsts, as2, ad2, ssum, E, N);
  hipMemsetAsync(bufB, 0, (size_t)N * HC * sizeof(float), stream);  // after GEMM consumed h1
  edge_aggregate<<<Etot, blk, 0, stream>>>(srcs, dsts, as2, ad2, ssum, bufA, bufB, E, N);

  // ---- head-mean + LN + residual + ELU ----
  final_kernel<<<N, dim3(64), 0, stream>>>(bufB, ident, bias2, g2, b2, (float*)d_out);
}

// Round 2
// 865.561 us; speedup vs baseline: 2.4636x; 2.4636x over previous
//
#include <hip/hip_runtime.h>
#include <math.h>

// Problem constants: N=50000, IN=128, H=4, C=64, HC=256
#define HH 4
#define CC 64
#define HC 256

static constexpr float NEG_SLOPE = 0.2f;
static constexpr float LN_EPS = 1e-5f;

// ---------------- GEMM: C[M,Ncol] = A[M,K] @ B[K,Ncol] (+ bias) ----------------
// 64x64 tile, BK=16, 256 threads, 4x4 per thread. fp32 (no fp32 MFMA on CDNA4).
__global__ __launch_bounds__(256) void gemm64(
    const float* __restrict__ A, const float* __restrict__ B,
    const float* __restrict__ bias, float* __restrict__ Cmat,
    int M, int Ncol, int K) {
  __shared__ float As[16][65];   // [k][m], +1 pad
  __shared__ float Bs[16][68];   // [k][n], +4 pad
  const int tid = threadIdx.x;
  const int tx = tid & 15, ty = tid >> 4;
  const int row0 = blockIdx.x * 64;
  const int col0 = blockIdx.y * 64;
  const int ar = tid >> 2;
  const int ak = (tid & 3) * 4;
  const int bk = tid >> 4;
  const int bn = (tid & 15) * 4;

  float acc[4][4] = {};
  for (int k0 = 0; k0 < K; k0 += 16) {
    float4 av = make_float4(0.f, 0.f, 0.f, 0.f);
    const int arow = row0 + ar;
    if (arow < M) av = *(const float4*)(A + (size_t)arow * K + k0 + ak);
    As[ak + 0][ar] = av.x; As[ak + 1][ar] = av.y;
    As[ak + 2][ar] = av.z; As[ak + 3][ar] = av.w;
    const float4 bv = *(const float4*)(B + (size_t)(k0 + bk) * Ncol + col0 + bn);
    *(float4*)(&Bs[bk][bn]) = bv;
    __syncthreads();
#pragma unroll
    for (int kk = 0; kk < 16; ++kk) {
      const float a0 = As[kk][ty * 4 + 0], a1 = As[kk][ty * 4 + 1];
      const float a2 = As[kk][ty * 4 + 2], a3 = As[kk][ty * 4 + 3];
      const float b0 = Bs[kk][tx * 4 + 0], b1 = Bs[kk][tx * 4 + 1];
      const float b2 = Bs[kk][tx * 4 + 2], b3 = Bs[kk][tx * 4 + 3];
      acc[0][0] += a0 * b0; acc[0][1] += a0 * b1; acc[0][2] += a0 * b2; acc[0][3] += a0 * b3;
      acc[1][0] += a1 * b0; acc[1][1] += a1 * b1; acc[1][2] += a1 * b2; acc[1][3] += a1 * b3;
      acc[2][0] += a2 * b0; acc[2][1] += a2 * b1; acc[2][2] += a2 * b2; acc[2][3] += a2 * b3;
      acc[3][0] += a3 * b0; acc[3][1] += a3 * b1; acc[3][2] += a3 * b2; acc[3][3] += a3 * b3;
    }
    __syncthreads();
  }
#pragma unroll
  for (int i = 0; i < 4; ++i) {
    const int r = row0 + ty * 4 + i;
    if (r < M) {
      const int ccol = col0 + tx * 4;
      float4 v = make_float4(acc[i][0], acc[i][1], acc[i][2], acc[i][3]);
      if (bias) {
        v.x += bias[ccol + 0]; v.y += bias[ccol + 1];
        v.z += bias[ccol + 2]; v.w += bias[ccol + 3];
      }
      *(float4*)(Cmat + (size_t)r * Ncol + ccol) = v;
    }
  }
}

// ---------------- per-node attention coefficients ----------------
__global__ __launch_bounds__(256) void alpha_kernel(
    const float* __restrict__ h, const float* __restrict__ att_src,
    const float* __restrict__ att_dst,
    float* __restrict__ as_, float* __restrict__ ad_) {
  const int n = blockIdx.x;
  const int i = threadIdx.x;
  const float v = h[(size_t)n * HC + i];
  float ps = v * att_src[i];
  float pd = v * att_dst[i];
#pragma unroll
  for (int off = 32; off > 0; off >>= 1) {
    ps += __shfl_down(ps, off);
    pd += __shfl_down(pd, off);
  }
  if ((i & 63) == 0) {
    const int hh = i >> 6;
    as_[n * HH + hh] = ps;
    ad_[n * HH + hh] = pd;
  }
}

// ================= CSR construction (per call; graph is identical for both layers) =================
__global__ __launch_bounds__(256) void deg_init(int* __restrict__ deg, int N) {
  const int i = blockIdx.x * 256 + threadIdx.x;
  if (i < N) deg[i] = 1;  // self-loop
}

__global__ __launch_bounds__(256) void deg_hist(
    const int* __restrict__ dsts, int* __restrict__ deg, int E) {
  const int e = blockIdx.x * 256 + threadIdx.x;
  if (e < E) atomicAdd(&deg[dsts[e]], 1);
}

// block-level inclusive scan: rowptr[g+1] = scan-within-block, bsum[b] = block total
__global__ __launch_bounds__(256) void scan_block(
    const int* __restrict__ deg, int* __restrict__ rowptr, int* __restrict__ bsum, int N) {
  const int b = blockIdx.x, t = threadIdx.x, g = b * 256 + t;
  const int lane = t & 63, w = t >> 6;
  int x = (g < N) ? deg[g] : 0;
#pragma unroll
  for (int off = 1; off < 64; off <<= 1) {
    const int y = __shfl_up(x, off);
    if (lane >= off) x += y;
  }
  __shared__ int wsum[4];
  if (lane == 63) wsum[w] = x;
  __syncthreads();
  int add = 0;
  for (int i = 0; i < w; ++i) add += wsum[i];
  x += add;
  if (g < N) rowptr[g + 1] = x;
  if (t == 255) bsum[b] = x;
}

// single-block exclusive scan of block sums (nb <= 256)
__global__ __launch_bounds__(256) void scan_top(int* __restrict__ bsum, int nb) {
  const int t = threadIdx.x;
  const int lane = t & 63, w = t >> 6;
  const int v = (t < nb) ? bsum[t] : 0;
  int x = v;
#pragma unroll
  for (int off = 1; off < 64; off <<= 1) {
    const int y = __shfl_up(x, off);
    if (lane >= off) x += y;
  }
  __shared__ int wsum[4];
  if (lane == 63) wsum[w] = x;
  __syncthreads();
  int add = 0;
  for (int i = 0; i < w; ++i) add += wsum[i];
  x += add;
  if (t < nb) bsum[t] = x - v;  // exclusive
}

__global__ __launch_bounds__(256) void scan_add(
    const int* __restrict__ bsum, int* __restrict__ rowptr,
    int* __restrict__ cursor, int N) {
  const int g = blockIdx.x * 256 + threadIdx.x;
  if (g == 0) rowptr[0] = 0;
  if (g < N) {
    const int v = rowptr[g + 1] + bsum[blockIdx.x];
    rowptr[g + 1] = v;
  }
}

// cursor[i] = rowptr[i] (separate pass so all rowptr writes are done)
__global__ __launch_bounds__(256) void copy_cursor(
    const int* __restrict__ rowptr, int* __restrict__ cursor, int N) {
  const int g = blockIdx.x * 256 + threadIdx.x;
  if (g < N) cursor[g] = rowptr[g];
}

__global__ __launch_bounds__(256) void csr_scatter(
    const int* __restrict__ srcs, const int* __restrict__ dsts,
    int* __restrict__ cursor, int* __restrict__ col, int E, int N) {
  const int e = blockIdx.x * 256 + threadIdx.x;
  if (e >= E + N) return;
  int s, d;
  if (e < E) { s = srcs[e]; d = dsts[e]; }
  else       { s = e - E; d = s; }
  const int pos = atomicAdd(&cursor[d], 1);
  col[pos] = s;
}

// ================= fused CSR aggregation =================
// layer 1: per-dst softmax-weighted aggregate + bias1 + LayerNorm + ELU -> h1 [N,256]
// block = 256 threads = (head hh = tid>>6) x (channel c = tid&63)
__global__ __launch_bounds__(256) void csr_agg_ln1(
    const int* __restrict__ rowptr, const int* __restrict__ col,
    const float* __restrict__ as_, const float* __restrict__ ad_,
    const float* __restrict__ hlin, const float* __restrict__ bias1,
    const float* __restrict__ g1, const float* __restrict__ b1,
    float* __restrict__ h1) {
  const int n = blockIdx.x;
  const int tid = threadIdx.x;
  const int hh = tid >> 6, c = tid & 63;
  const float adv = ad_[n * 4 + hh];
  const int beg = rowptr[n], end = rowptr[n + 1];
  float acc = 0.f, wsum = 0.f;
  for (int i = beg; i < end; ++i) {
    const int s = col[i];
    float v = as_[s * 4 + hh] + adv;
    v = v > 0.f ? v : NEG_SLOPE * v;
    const float w = expf(v);
    wsum += w;
    acc += w * hlin[(size_t)s * HC + hh * 64 + c];
  }
  const float val = acc / wsum + bias1[tid];
  // block LayerNorm over 256 channels
  float s1 = val, s2 = val * val;
#pragma unroll
  for (int off = 32; off > 0; off >>= 1) {
    s1 += __shfl_down(s1, off);
    s2 += __shfl_down(s2, off);
  }
  __shared__ float ws1[4], ws2[4];
  if ((tid & 63) == 0) { ws1[hh] = s1; ws2[hh] = s2; }
  __syncthreads();
  const float tot1 = ws1[0] + ws1[1] + ws1[2] + ws1[3];
  const float tot2 = ws2[0] + ws2[1] + ws2[2] + ws2[3];
  const float mu = tot1 * (1.0f / HC);
  const float var = tot2 * (1.0f / HC) - mu * mu;
  float y = (val - mu) * rsqrtf(var + LN_EPS) * g1[tid] + b1[tid];
  y = y > 0.f ? y : expm1f(y);
  h1[(size_t)n * HC + tid] = y;
}

// layer 2: aggregate + head-mean + bias2 + LayerNorm + residual + ELU -> out [N,64]
__global__ __launch_bounds__(256) void csr_agg_final(
    const int* __restrict__ rowptr, const int* __restrict__ col,
    const float* __restrict__ as_, const float* __restrict__ ad_,
    const float* __restrict__ hlin, const float* __restrict__ ident,
    const float* __restrict__ bias2, const float* __restrict__ g2,
    const float* __restrict__ b2, float* __restrict__ out) {
  const int n = blockIdx.x;
  const int tid = threadIdx.x;
  const int hh = tid >> 6, c = tid & 63;
  const float adv = ad_[n * 4 + hh];
  const int beg = rowptr[n], end = rowptr[n + 1];
  float acc = 0.f, wsum = 0.f;
  for (int i = beg; i < end; ++i) {
    const int s = col[i];
    float v = as_[s * 4 + hh] + adv;
    v = v > 0.f ? v : NEG_SLOPE * v;
    const float w = expf(v);
    wsum += w;
    acc += w * hlin[(size_t)s * HC + hh * 64 + c];
  }
  __shared__ float sm[4][64];
  sm[hh][c] = acc / wsum;
  __syncthreads();
  if (tid < 64) {  // first wave: head-mean + LN(64) + residual + ELU
    float v = 0.25f * (sm[0][tid] + sm[1][tid] + sm[2][tid] + sm[3][tid]) + bias2[tid];
    float s1 = v, s2 = v * v;
#pragma unroll
    for (int off = 32; off > 0; off >>= 1) {
      s1 += __shfl_down(s1, off);
      s2 += __shfl_down(s2, off);
    }
    s1 = __shfl(s1, 0);
    s2 = __shfl(s2, 0);
    const float mu = s1 * (1.0f / 64.0f);
    const float var = s2 * (1.0f / 64.0f) - mu * mu;
    float y = (v - mu) * rsqrtf(var + LN_EPS) * g2[tid] + b2[tid];
    y += ident[(size_t)n * 64 + tid];
    out[(size_t)n * 64 + tid] = y > 0.f ? y : expm1f(y);
  }
}

extern "C" void kernel_launch(void* const* d_in, const int* in_sizes, int n_in,
                              void* d_out, int out_size, void* d_ws, size_t ws_size,
                              hipStream_t stream) {
  const float* x        = (const float*)d_in[0];
  const int*   ei       = (const int*)d_in[1];
  const float* W1       = (const float*)d_in[2];
  const float* att_src1 = (const float*)d_in[3];
  const float* att_dst1 = (const float*)d_in[4];
  const float* bias1    = (const float*)d_in[5];
  const float* g1       = (const float*)d_in[6];
  const float* b1       = (const float*)d_in[7];
  const float* W2       = (const float*)d_in[8];
  const float* att_src2 = (const float*)d_in[9];
  const float* att_dst2 = (const float*)d_in[10];
  const float* bias2    = (const float*)d_in[11];
  const float* g2       = (const float*)d_in[12];
  const float* b2       = (const float*)d_in[13];
  const float* Wres     = (const float*)d_in[14];
  const float* bres     = (const float*)d_in[15];

  const int N = in_sizes[0] / 128;   // 50000
  const int E = in_sizes[1] / 2;     // 800000
  const int IN = 128;
  const int Etot = E + N;

  const int* srcs = ei;
  const int* dsts = ei + E;

  // workspace layout
  float* ws    = (float*)d_ws;
  float* ident = ws;                          // N*64
  float* bufA  = ident + (size_t)N * 64;      // N*256 (h_lin for current layer)
  float* h1    = bufA + (size_t)N * HC;       // N*256
  float* as_   = h1 + (size_t)N * HC;         // N*4
  float* ad_   = as_ + (size_t)N * HH;        // N*4
  int* rowptr  = (int*)(ad_ + (size_t)N * HH);// N+1
  int* deg     = rowptr + (N + 1);            // N (deg, then cursor)
  int* bsum    = deg + N;                     // 256
  int* col     = bsum + 256;                  // Etot

  const int mblocks = (N + 63) / 64;
  const int nscan = (N + 255) / 256;
  dim3 blk(256);

  // ---- CSR build (shared by both layers) ----
  deg_init<<<nscan, blk, 0, stream>>>(deg, N);
  deg_hist<<<(E + 255) / 256, blk, 0, stream>>>(dsts, deg, E);
  scan_block<<<nscan, blk, 0, stream>>>(deg, rowptr, bsum, N);
  scan_top<<<1, blk, 0, stream>>>(bsum, nscan);
  scan_add<<<nscan, blk, 0, stream>>>(bsum, rowptr, deg, N);
  copy_cursor<<<nscan, blk, 0, stream>>>(rowptr, deg, N);
  csr_scatter<<<(Etot + 255) / 256, blk, 0, stream>>>(srcs, dsts, deg, col, E, N);

  // residual projection
  gemm64<<<dim3(mblocks, 1), blk, 0, stream>>>(x, Wres, bres, ident, N, 64, IN);

  // ---- GAT layer 1 ----
  gemm64<<<dim3(mblocks, 4), blk, 0, stream>>>(x, W1, nullptr, bufA, N, HC, IN);
  alpha_kernel<<<N, blk, 0, stream>>>(bufA, att_src1, att_dst1, as_, ad_);
  csr_agg_ln1<<<N, blk, 0, stream>>>(rowptr, col, as_, ad_, bufA, bias1, g1, b1, h1);

  // ---- GAT layer 2 ----
  gemm64<<<dim3(mblocks, 4), blk, 0, stream>>>(h1, W2, nullptr, bufA, N, HC, HC);
  alpha_kernel<<<N, blk, 0, stream>>>(bufA, att_src2, att_dst2, as_, ad_);
  csr_agg_final<<<N, blk, 0, stream>>>(rowptr, col, as_, ad_, bufA, ident,
                                       bias2, g2, b2, (float*)d_out);
}

// Round 3
// 743.631 us; speedup vs baseline: 2.8676x; 1.1640x over previous
//
#include <hip/hip_runtime.h>
#include <math.h>

// Problem constants: N=50000, IN=128, H=4, C=64, HC=256
#define HH 4
#define CC 64
#define HC 256

static constexpr float NEG_SLOPE = 0.2f;
static constexpr float LN_EPS = 1e-5f;

typedef __attribute__((ext_vector_type(8))) short short8;
typedef __attribute__((ext_vector_type(4))) float floatx4;

__device__ __forceinline__ float bf2f(unsigned short u) {
  return __uint_as_float(((unsigned int)u) << 16);
}
__device__ __forceinline__ unsigned short f2bf(float f) {
  unsigned int u = __float_as_uint(f);
  u = (u + 0x7fff + ((u >> 16) & 1)) >> 16;  // round-to-nearest-even
  return (unsigned short)u;
}
__device__ __forceinline__ void store_out(float* p, float v) { *p = v; }
__device__ __forceinline__ void store_out(unsigned short* p, float v) { *p = f2bf(v); }

// ---------------- dtype prep ----------------
__global__ __launch_bounds__(256) void cvt_bf16_x4(
    const float* __restrict__ src, unsigned short* __restrict__ dst, int n4) {
  const int i = blockIdx.x * 256 + threadIdx.x;
  if (i < n4) {
    const float4 v = ((const float4*)src)[i];
    ushort4 o;
    o.x = f2bf(v.x); o.y = f2bf(v.y); o.z = f2bf(v.z); o.w = f2bf(v.w);
    ((ushort4*)dst)[i] = o;
  }
}

// W [K,Nc] fp32 -> WT [Nc,K] bf16 (tiny matrices)
__global__ __launch_bounds__(256) void cvt_transpose(
    const float* __restrict__ W, unsigned short* __restrict__ WT, int K, int Nc) {
  const int idx = blockIdx.x * 256 + threadIdx.x;
  if (idx < K * Nc) {
    const int k = idx / Nc, n = idx - k * Nc;
    WT[n * K + k] = f2bf(W[idx]);
  }
}

// ---------------- bf16 MFMA GEMM: C[M,Nc] = A[M,K] @ B[K,Nc] (+bias) ----------------
// A bf16 [M,K]; BT bf16 [Nc,K] (pre-transposed). Tile 64x64, BK=32, 4 waves.
// Wave w computes rows [w*16, w*16+16) x 64 cols via 4 mfma_f32_16x16x32_bf16 per k-step.
template <typename OutT>
__global__ __launch_bounds__(256) void gemm_bf16(
    const unsigned short* __restrict__ A, const unsigned short* __restrict__ BT,
    const float* __restrict__ bias, OutT* __restrict__ C,
    int M, int Nc, int K) {
  __shared__ unsigned short As[64][40];  // [m][k], k-stride 40 halves (80B) kills conflicts
  __shared__ unsigned short Bs[64][40];  // [n][k]
  const int tid = threadIdx.x;
  const int w = tid >> 6;
  const int lane = tid & 63;
  const int q = lane >> 4;       // quad 0..3
  const int mr = lane & 15;
  const int row0 = blockIdx.x * 64;
  const int col0 = blockIdx.y * 64;
  const int sr = tid >> 2;       // staging row/col 0..63
  const int sk = (tid & 3) * 8;  // staging k offset

  floatx4 acc[4] = {};

  for (int k0 = 0; k0 < K; k0 += 32) {
    const int arow = row0 + sr;
    short8 av8 = {};
    if (arow < M) av8 = *(const short8*)(A + (size_t)arow * K + k0 + sk);
    *(short8*)(&As[sr][sk]) = av8;
    *(short8*)(&Bs[sr][sk]) = *(const short8*)(BT + (size_t)(col0 + sr) * K + k0 + sk);
    __syncthreads();
    const short8 af = *(const short8*)(&As[w * 16 + mr][q * 8]);
#pragma unroll
    for (int ct = 0; ct < 4; ++ct) {
      const short8 bf = *(const short8*)(&Bs[ct * 16 + mr][q * 8]);
      acc[ct] = __builtin_amdgcn_mfma_f32_16x16x32_bf16(af, bf, acc[ct], 0, 0, 0);
    }
    __syncthreads();
  }
  // C/D layout: col=lane&15, row=q*4+reg  [m89-verified]
#pragma unroll
  for (int ct = 0; ct < 4; ++ct) {
#pragma unroll
    for (int r = 0; r < 4; ++r) {
      const int row = row0 + w * 16 + q * 4 + r;
      if (row < M) {
        const int cc = col0 + ct * 16 + mr;
        float v = acc[ct][r];
        if (bias) v += bias[cc];
        store_out(C + (size_t)row * Nc + cc, v);
      }
    }
  }
}

// ---------------- per-node attention coefficients (bf16 h) ----------------
__global__ __launch_bounds__(256) void alpha_kernel(
    const unsigned short* __restrict__ h, const float* __restrict__ att_src,
    const float* __restrict__ att_dst,
    float* __restrict__ as_, float* __restrict__ ad_) {
  const int n = blockIdx.x;
  const int i = threadIdx.x;
  const float v = bf2f(h[(size_t)n * HC + i]);
  float ps = v * att_src[i];
  float pd = v * att_dst[i];
#pragma unroll
  for (int off = 32; off > 0; off >>= 1) {
    ps += __shfl_down(ps, off);
    pd += __shfl_down(pd, off);
  }
  if ((i & 63) == 0) {
    const int hh = i >> 6;
    as_[n * HH + hh] = ps;
    ad_[n * HH + hh] = pd;
  }
}

// ================= CSR construction =================
__global__ __launch_bounds__(256) void deg_init(int* __restrict__ deg, int N) {
  const int i = blockIdx.x * 256 + threadIdx.x;
  if (i < N) deg[i] = 1;  // self-loop
}

__global__ __launch_bounds__(256) void deg_hist(
    const int* __restrict__ dsts, int* __restrict__ deg, int E) {
  const int e = blockIdx.x * 256 + threadIdx.x;
  if (e < E) atomicAdd(&deg[dsts[e]], 1);
}

__global__ __launch_bounds__(256) void scan_block(
    const int* __restrict__ deg, int* __restrict__ rowptr, int* __restrict__ bsum, int N) {
  const int b = blockIdx.x, t = threadIdx.x, g = b * 256 + t;
  const int lane = t & 63, w = t >> 6;
  int x = (g < N) ? deg[g] : 0;
#pragma unroll
  for (int off = 1; off < 64; off <<= 1) {
    const int y = __shfl_up(x, off);
    if (lane >= off) x += y;
  }
  __shared__ int wsum[4];
  if (lane == 63) wsum[w] = x;
  __syncthreads();
  int add = 0;
  for (int i = 0; i < w; ++i) add += wsum[i];
  x += add;
  if (g < N) rowptr[g + 1] = x;
  if (t == 255) bsum[b] = x;
}

__global__ __launch_bounds__(256) void scan_top(int* __restrict__ bsum, int nb) {
  const int t = threadIdx.x;
  const int lane = t & 63, w = t >> 6;
  const int v = (t < nb) ? bsum[t] : 0;
  int x = v;
#pragma unroll
  for (int off = 1; off < 64; off <<= 1) {
    const int y = __shfl_up(x, off);
    if (lane >= off) x += y;
  }
  __shared__ int wsum[4];
  if (lane == 63) wsum[w] = x;
  __syncthreads();
  int add = 0;
  for (int i = 0; i < w; ++i) add += wsum[i];
  x += add;
  if (t < nb) bsum[t] = x - v;  // exclusive
}

__global__ __launch_bounds__(256) void scan_add(
    const int* __restrict__ bsum, int* __restrict__ rowptr, int N) {
  const int g = blockIdx.x * 256 + threadIdx.x;
  if (g == 0) rowptr[0] = 0;
  if (g < N) rowptr[g + 1] += bsum[blockIdx.x];
}

__global__ __launch_bounds__(256) void copy_cursor(
    const int* __restrict__ rowptr, int* __restrict__ cursor, int N) {
  const int g = blockIdx.x * 256 + threadIdx.x;
  if (g < N) cursor[g] = rowptr[g];
}

__global__ __launch_bounds__(256) void csr_scatter(
    const int* __restrict__ srcs, const int* __restrict__ dsts,
    int* __restrict__ cursor, int* __restrict__ col, int E, int N) {
  const int e = blockIdx.x * 256 + threadIdx.x;
  if (e >= E + N) return;
  int s, d;
  if (e < E) { s = srcs[e]; d = dsts[e]; }
  else       { s = e - E; d = s; }
  const int pos = atomicAdd(&cursor[d], 1);
  col[pos] = s;
}

// ================= fused CSR aggregation (wave-cooperative weights) =================
// layer 1: aggregate + bias1 + LN(256) + ELU -> h1 bf16 [N,256]
__global__ __launch_bounds__(256) void csr_agg_ln1(
    const int* __restrict__ rowptr, const int* __restrict__ col,
    const float* __restrict__ as_, const float* __restrict__ ad_,
    const unsigned short* __restrict__ hlin, const float* __restrict__ bias1,
    const float* __restrict__ g1, const float* __restrict__ b1,
    unsigned short* __restrict__ h1) {
  const int n = blockIdx.x;
  const int tid = threadIdx.x;
  const int hh = tid >> 6, lane = tid & 63;
  const float adv = ad_[n * 4 + hh];
  const int beg = rowptr[n], end = rowptr[n + 1];
  const unsigned short* hp = hlin + tid;  // tid == hh*64 + c
  float acc = 0.f, wsum = 0.f;
  for (int off = beg; off < end; off += 64) {
    const int len = min(64, end - off);
    int s_l = 0;
    float w_l = 0.f;
    if (lane < len) {
      s_l = col[off + lane];
      float v = as_[s_l * 4 + hh] + adv;
      v = v > 0.f ? v : NEG_SLOPE * v;
      w_l = expf(v);
    }
    wsum += w_l;
    for (int j = 0; j < len; ++j) {
      const int s = __shfl(s_l, j);
      const float w = __shfl(w_l, j);
      acc += w * bf2f(hp[(size_t)s * HC]);
    }
  }
#pragma unroll
  for (int off = 32; off > 0; off >>= 1) wsum += __shfl_xor(wsum, off);
  const float val = acc / wsum + bias1[tid];
  // LayerNorm over 256
  float s1 = val, s2 = val * val;
#pragma unroll
  for (int off = 32; off > 0; off >>= 1) {
    s1 += __shfl_down(s1, off);
    s2 += __shfl_down(s2, off);
  }
  __shared__ float ws1[4], ws2[4];
  if (lane == 0) { ws1[hh] = s1; ws2[hh] = s2; }
  __syncthreads();
  const float tot1 = ws1[0] + ws1[1] + ws1[2] + ws1[3];
  const float tot2 = ws2[0] + ws2[1] + ws2[2] + ws2[3];
  const float mu = tot1 * (1.0f / HC);
  const float var = tot2 * (1.0f / HC) - mu * mu;
  float y = (val - mu) * rsqrtf(var + LN_EPS) * g1[tid] + b1[tid];
  y = y > 0.f ? y : expm1f(y);
  h1[(size_t)n * HC + tid] = f2bf(y);
}

// layer 2: aggregate + head-mean + bias2 + LN(64) + residual + ELU -> out fp32 [N,64]
__global__ __launch_bounds__(256) void csr_agg_final(
    const int* __restrict__ rowptr, const int* __restrict__ col,
    const float* __restrict__ as_, const float* __restrict__ ad_,
    const unsigned short* __restrict__ hlin, const float* __restrict__ ident,
    const float* __restrict__ bias2, const float* __restrict__ g2,
    const float* __restrict__ b2, float* __restrict__ out) {
  const int n = blockIdx.x;
  const int tid = threadIdx.x;
  const int hh = tid >> 6, lane = tid & 63;
  const float adv = ad_[n * 4 + hh];
  const int beg = rowptr[n], end = rowptr[n + 1];
  const unsigned short* hp = hlin + tid;
  float acc = 0.f, wsum = 0.f;
  for (int off = beg; off < end; off += 64) {
    const int len = min(64, end - off);
    int s_l = 0;
    float w_l = 0.f;
    if (lane < len) {
      s_l = col[off + lane];
      float v = as_[s_l * 4 + hh] + adv;
      v = v > 0.f ? v : NEG_SLOPE * v;
      w_l = expf(v);
    }
    wsum += w_l;
    for (int j = 0; j < len; ++j) {
      const int s = __shfl(s_l, j);
      const float w = __shfl(w_l, j);
      acc += w * bf2f(hp[(size_t)s * HC]);
    }
  }
#pragma unroll
  for (int off = 32; off > 0; off >>= 1) wsum += __shfl_xor(wsum, off);
  __shared__ float sm[4][64];
  sm[hh][lane] = acc / wsum;
  __syncthreads();
  if (tid < 64) {
    float v = 0.25f * (sm[0][tid] + sm[1][tid] + sm[2][tid] + sm[3][tid]) + bias2[tid];
    float s1 = v, s2 = v * v;
#pragma unroll
    for (int off = 32; off > 0; off >>= 1) {
      s1 += __shfl_down(s1, off);
      s2 += __shfl_down(s2, off);
    }
    s1 = __shfl(s1, 0);
    s2 = __shfl(s2, 0);
    const float mu = s1 * (1.0f / 64.0f);
    const float var = s2 * (1.0f / 64.0f) - mu * mu;
    float y = (v - mu) * rsqrtf(var + LN_EPS) * g2[tid] + b2[tid];
    y += ident[(size_t)n * 64 + tid];
    out[(size_t)n * 64 + tid] = y > 0.f ? y : expm1f(y);
  }
}

extern "C" void kernel_launch(void* const* d_in, const int* in_sizes, int n_in,
                              void* d_out, int out_size, void* d_ws, size_t ws_size,
                              hipStream_t stream) {
  const float* x        = (const float*)d_in[0];
  const int*   ei       = (const int*)d_in[1];
  const float* W1       = (const float*)d_in[2];
  const float* att_src1 = (const float*)d_in[3];
  const float* att_dst1 = (const float*)d_in[4];
  const float* bias1    = (const float*)d_in[5];
  const float* g1       = (const float*)d_in[6];
  const float* b1       = (const float*)d_in[7];
  const float* W2       = (const float*)d_in[8];
  const float* att_src2 = (const float*)d_in[9];
  const float* att_dst2 = (const float*)d_in[10];
  const float* bias2    = (const float*)d_in[11];
  const float* g2       = (const float*)d_in[12];
  const float* b2       = (const float*)d_in[13];
  const float* Wres     = (const float*)d_in[14];
  const float* bres     = (const float*)d_in[15];

  const int N = in_sizes[0] / 128;   // 50000
  const int E = in_sizes[1] / 2;     // 800000
  const int IN = 128;
  const int Etot = E + N;

  const int* srcs = ei;
  const int* dsts = ei + E;

  // workspace layout (16B-aligned segments)
  char* p = (char*)d_ws;
  float* ident = (float*)p;            p += (size_t)N * 64 * 4;
  float* as_   = (float*)p;            p += (size_t)N * HH * 4;
  float* ad_   = (float*)p;            p += (size_t)N * HH * 4;
  int* rowptr  = (int*)p;              p += (size_t)(N + 4) * 4;
  int* deg     = (int*)p;              p += (size_t)N * 4;
  int* bsum    = (int*)p;              p += 256 * 4;
  int* col     = (int*)p;              p += (size_t)Etot * 4;
  p = (char*)(((uintptr_t)p + 15) & ~(uintptr_t)15);
  unsigned short* xb    = (unsigned short*)p; p += (size_t)N * IN * 2;
  unsigned short* hlinb = (unsigned short*)p; p += (size_t)N * HC * 2;
  unsigned short* h1b   = (unsigned short*)p; p += (size_t)N * HC * 2;
  unsigned short* wt1   = (unsigned short*)p; p += (size_t)IN * HC * 2;
  unsigned short* wt2   = (unsigned short*)p; p += (size_t)HC * HC * 2;
  unsigned short* wtres = (unsigned short*)p; p += (size_t)IN * 64 * 2;

  const int mblocks = (N + 63) / 64;
  const int nscan = (N + 255) / 256;
  dim3 blk(256);

  // ---- dtype prep ----
  cvt_bf16_x4<<<(N * IN / 4 + 255) / 256, blk, 0, stream>>>(x, xb, N * IN / 4);
  cvt_transpose<<<(IN * HC + 255) / 256, blk, 0, stream>>>(W1, wt1, IN, HC);
  cvt_transpose<<<(HC * HC + 255) / 256, blk, 0, stream>>>(W2, wt2, HC, HC);
  cvt_transpose<<<(IN * 64 + 255) / 256, blk, 0, stream>>>(Wres, wtres, IN, 64);

  // ---- CSR build ----
  deg_init<<<nscan, blk, 0, stream>>>(deg, N);
  deg_hist<<<(E + 255) / 256, blk, 0, stream>>>(dsts, deg, E);
  scan_block<<<nscan, blk, 0, stream>>>(deg, rowptr, bsum, N);
  scan_top<<<1, blk, 0, stream>>>(bsum, nscan);
  scan_add<<<nscan, blk, 0, stream>>>(bsum, rowptr, N);
  copy_cursor<<<nscan, blk, 0, stream>>>(rowptr, deg, N);
  csr_scatter<<<(Etot + 255) / 256, blk, 0, stream>>>(srcs, dsts, deg, col, E, N);

  // residual projection (fp32 out)
  gemm_bf16<float><<<dim3(mblocks, 1), blk, 0, stream>>>(xb, wtres, bres, ident, N, 64, IN);

  // ---- GAT layer 1 ----
  gemm_bf16<unsigned short><<<dim3(mblocks, 4), blk, 0, stream>>>(xb, wt1, nullptr, hlinb, N, HC, IN);
  alpha_kernel<<<N, blk, 0, stream>>>(hlinb, att_src1, att_dst1, as_, ad_);
  csr_agg_ln1<<<N, blk, 0, stream>>>(rowptr, col, as_, ad_, hlinb, bias1, g1, b1, h1b);

  // ---- GAT layer 2 ----
  gemm_bf16<unsigned short><<<dim3(mblocks, 4), blk, 0, stream>>>(h1b, wt2, nullptr, hlinb, N, HC, HC);
  alpha_kernel<<<N, blk, 0, stream>>>(hlinb, att_src2, att_dst2, as_, ad_);
  csr_agg_final<<<N, blk, 0, stream>>>(rowptr, col, as_, ad_, hlinb, ident,
                                       bias2, g2, b2, (float*)d_out);
}

// Round 4
// 543.710 us; speedup vs baseline: 3.9220x; 1.3677x over previous
//
#include <hip/hip_runtime.h>
#include <math.h>

// Problem constants: N=50000, IN=128, H=4, C=64, HC=256
#define HH 4
#define CC 64
#define HC 256

static constexpr float NEG_SLOPE = 0.2f;
static constexpr float LN_EPS = 1e-5f;

typedef __attribute__((ext_vector_type(8))) short short8;
typedef __attribute__((ext_vector_type(4))) float floatx4;

__device__ __forceinline__ float bf2f(unsigned short u) {
  return __uint_as_float(((unsigned int)u) << 16);
}
__device__ __forceinline__ unsigned short f2bf(float f) {
  unsigned int u = __float_as_uint(f);
  u = (u + 0x7fff + ((u >> 16) & 1)) >> 16;  // round-to-nearest-even
  return (unsigned short)u;
}
__device__ __forceinline__ void store_out(float* p, float v) { *p = v; }
__device__ __forceinline__ void store_out(unsigned short* p, float v) { *p = f2bf(v); }

// ---------------- dtype prep ----------------
__global__ __launch_bounds__(256) void cvt_bf16_x4(
    const float* __restrict__ src, unsigned short* __restrict__ dst, int n4) {
  const int i = blockIdx.x * 256 + threadIdx.x;
  if (i < n4) {
    const float4 v = ((const float4*)src)[i];
    ushort4 o;
    o.x = f2bf(v.x); o.y = f2bf(v.y); o.z = f2bf(v.z); o.w = f2bf(v.w);
    ((ushort4*)dst)[i] = o;
  }
}

// W [K,Nc] fp32 -> WT [Nc,K] bf16 (tiny matrices)
__global__ __launch_bounds__(256) void cvt_transpose(
    const float* __restrict__ W, unsigned short* __restrict__ WT, int K, int Nc) {
  const int idx = blockIdx.x * 256 + threadIdx.x;
  if (idx < K * Nc) {
    const int k = idx / Nc, n = idx - k * Nc;
    WT[n * K + k] = f2bf(W[idx]);
  }
}

// ---------------- bf16 MFMA GEMM: C[M,Nc] = A[M,K] @ B[K,Nc] (+bias) ----------------
template <typename OutT>
__global__ __launch_bounds__(256) void gemm_bf16(
    const unsigned short* __restrict__ A, const unsigned short* __restrict__ BT,
    const float* __restrict__ bias, OutT* __restrict__ C,
    int M, int Nc, int K) {
  __shared__ unsigned short As[64][40];
  __shared__ unsigned short Bs[64][40];
  const int tid = threadIdx.x;
  const int w = tid >> 6;
  const int lane = tid & 63;
  const int q = lane >> 4;
  const int mr = lane & 15;
  const int row0 = blockIdx.x * 64;
  const int col0 = blockIdx.y * 64;
  const int sr = tid >> 2;
  const int sk = (tid & 3) * 8;

  floatx4 acc[4] = {};

  for (int k0 = 0; k0 < K; k0 += 32) {
    const int arow = row0 + sr;
    short8 av8 = {};
    if (arow < M) av8 = *(const short8*)(A + (size_t)arow * K + k0 + sk);
    *(short8*)(&As[sr][sk]) = av8;
    *(short8*)(&Bs[sr][sk]) = *(const short8*)(BT + (size_t)(col0 + sr) * K + k0 + sk);
    __syncthreads();
    const short8 af = *(const short8*)(&As[w * 16 + mr][q * 8]);
#pragma unroll
    for (int ct = 0; ct < 4; ++ct) {
      const short8 bf = *(const short8*)(&Bs[ct * 16 + mr][q * 8]);
      acc[ct] = __builtin_amdgcn_mfma_f32_16x16x32_bf16(af, bf, acc[ct], 0, 0, 0);
    }
    __syncthreads();
  }
#pragma unroll
  for (int ct = 0; ct < 4; ++ct) {
#pragma unroll
    for (int r = 0; r < 4; ++r) {
      const int row = row0 + w * 16 + q * 4 + r;
      if (row < M) {
        const int cc = col0 + ct * 16 + mr;
        float v = acc[ct][r];
        if (bias) v += bias[cc];
        store_out(C + (size_t)row * Nc + cc, v);
      }
    }
  }
}

// ---------------- per-node attention coefficients (bf16 h) ----------------
__global__ __launch_bounds__(256) void alpha_kernel(
    const unsigned short* __restrict__ h, const float* __restrict__ att_src,
    const float* __restrict__ att_dst,
    float* __restrict__ as_, float* __restrict__ ad_) {
  const int n = blockIdx.x;
  const int i = threadIdx.x;
  const float v = bf2f(h[(size_t)n * HC + i]);
  float ps = v * att_src[i];
  float pd = v * att_dst[i];
#pragma unroll
  for (int off = 32; off > 0; off >>= 1) {
    ps += __shfl_down(ps, off);
    pd += __shfl_down(pd, off);
  }
  if ((i & 63) == 0) {
    const int hh = i >> 6;
    as_[n * HH + hh] = ps;
    ad_[n * HH + hh] = pd;
  }
}

// ================= CSR construction =================
__global__ __launch_bounds__(256) void deg_init(int* __restrict__ deg, int N) {
  const int i = blockIdx.x * 256 + threadIdx.x;
  if (i < N) deg[i] = 1;  // self-loop
}

__global__ __launch_bounds__(256) void deg_hist(
    const int* __restrict__ dsts, int* __restrict__ deg, int E) {
  const int e = blockIdx.x * 256 + threadIdx.x;
  if (e < E) atomicAdd(&deg[dsts[e]], 1);
}

__global__ __launch_bounds__(256) void scan_block(
    const int* __restrict__ deg, int* __restrict__ rowptr, int* __restrict__ bsum, int N) {
  const int b = blockIdx.x, t = threadIdx.x, g = b * 256 + t;
  const int lane = t & 63, w = t >> 6;
  int x = (g < N) ? deg[g] : 0;
#pragma unroll
  for (int off = 1; off < 64; off <<= 1) {
    const int y = __shfl_up(x, off);
    if (lane >= off) x += y;
  }
  __shared__ int wsum[4];
  if (lane == 63) wsum[w] = x;
  __syncthreads();
  int add = 0;
  for (int i = 0; i < w; ++i) add += wsum[i];
  x += add;
  if (g < N) rowptr[g + 1] = x;
  if (t == 255) bsum[b] = x;
}

__global__ __launch_bounds__(256) void scan_top(int* __restrict__ bsum, int nb) {
  const int t = threadIdx.x;
  const int lane = t & 63, w = t >> 6;
  const int v = (t < nb) ? bsum[t] : 0;
  int x = v;
#pragma unroll
  for (int off = 1; off < 64; off <<= 1) {
    const int y = __shfl_up(x, off);
    if (lane >= off) x += y;
  }
  __shared__ int wsum[4];
  if (lane == 63) wsum[w] = x;
  __syncthreads();
  int add = 0;
  for (int i = 0; i < w; ++i) add += wsum[i];
  x += add;
  if (t < nb) bsum[t] = x - v;  // exclusive
}

__global__ __launch_bounds__(256) void scan_add(
    const int* __restrict__ bsum, int* __restrict__ rowptr, int N) {
  const int g = blockIdx.x * 256 + threadIdx.x;
  if (g == 0) rowptr[0] = 0;
  if (g < N) rowptr[g + 1] += bsum[blockIdx.x];
}

__global__ __launch_bounds__(256) void copy_cursor(
    const int* __restrict__ rowptr, int* __restrict__ cursor, int N) {
  const int g = blockIdx.x * 256 + threadIdx.x;
  if (g < N) cursor[g] = rowptr[g];
}

__global__ __launch_bounds__(256) void csr_scatter(
    const int* __restrict__ srcs, const int* __restrict__ dsts,
    int* __restrict__ cursor, int* __restrict__ col, int E, int N) {
  const int e = blockIdx.x * 256 + threadIdx.x;
  if (e >= E + N) return;
  int s, d;
  if (e < E) { s = srcs[e]; d = dsts[e]; }
  else       { s = e - E; d = s; }
  const int pos = atomicAdd(&cursor[d], 1);
  col[pos] = s;
}

// ================= fused CSR aggregation (8-edge vectorized gather) =================
// Each wave handles one head. Per 64-edge chunk: lane computes weight for edge `lane`.
// Gather: lane loads short8 (16B) of edge (j + lane>>3), channels (lane&7)*8..+7 —
// one dwordx4 per 8 edges per wave. Cross-subgroup reduce at the end, LN via LDS.
__global__ __launch_bounds__(256) void csr_agg_ln1(
    const int* __restrict__ rowptr, const int* __restrict__ col,
    const float* __restrict__ as_, const float* __restrict__ ad_,
    const unsigned short* __restrict__ hlin, const float* __restrict__ bias1,
    const float* __restrict__ g1, const float* __restrict__ b1,
    unsigned short* __restrict__ h1) {
  const int n = blockIdx.x;
  const int tid = threadIdx.x;
  const int hh = tid >> 6, lane = tid & 63;
  const int sub = lane >> 3, cg = lane & 7;
  const unsigned short* hbase = hlin + hh * 64 + cg * 8;
  const float adv = ad_[n * 4 + hh];
  const int beg = rowptr[n], end = rowptr[n + 1];
  float acc[8] = {};
  float wsum = 0.f;
  for (int off = beg; off < end; off += 64) {
    const int len = min(64, end - off);
    int s_l = 0;
    float w_l = 0.f;
    if (lane < len) {
      s_l = col[off + lane];
      float v = as_[s_l * 4 + hh] + adv;
      v = v > 0.f ? v : NEG_SLOPE * v;
      w_l = expf(v);
    }
    wsum += w_l;
    for (int j = 0; j < len; j += 8) {
      const int s = __shfl(s_l, j + sub);
      const float w = __shfl(w_l, j + sub);
      const short8 hv = *(const short8*)(hbase + (size_t)s * HC);
#pragma unroll
      for (int t = 0; t < 8; ++t) acc[t] += w * bf2f((unsigned short)hv[t]);
    }
  }
  // reduce weights across all 64 lanes; accumulators across the 8 subgroups
#pragma unroll
  for (int off = 32; off > 0; off >>= 1) wsum += __shfl_xor(wsum, off);
#pragma unroll
  for (int t = 0; t < 8; ++t) {
    acc[t] += __shfl_xor(acc[t], 8);
    acc[t] += __shfl_xor(acc[t], 16);
    acc[t] += __shfl_xor(acc[t], 32);
  }
  __shared__ float vals[HC];
  if (sub == 0) {
    const float inv = 1.0f / wsum;
#pragma unroll
    for (int t = 0; t < 8; ++t) vals[hh * 64 + cg * 8 + t] = acc[t] * inv;
  }
  __syncthreads();
  const float val = vals[tid] + bias1[tid];
  // LayerNorm over 256
  float s1 = val, s2 = val * val;
#pragma unroll
  for (int off = 32; off > 0; off >>= 1) {
    s1 += __shfl_down(s1, off);
    s2 += __shfl_down(s2, off);
  }
  __shared__ float ws1[4], ws2[4];
  if (lane == 0) { ws1[hh] = s1; ws2[hh] = s2; }
  __syncthreads();
  const float tot1 = ws1[0] + ws1[1] + ws1[2] + ws1[3];
  const float tot2 = ws2[0] + ws2[1] + ws2[2] + ws2[3];
  const float mu = tot1 * (1.0f / HC);
  const float var = tot2 * (1.0f / HC) - mu * mu;
  float y = (val - mu) * rsqrtf(var + LN_EPS) * g1[tid] + b1[tid];
  y = y > 0.f ? y : expm1f(y);
  h1[(size_t)n * HC + tid] = f2bf(y);
}

// layer 2: aggregate + head-mean + bias2 + LN(64) + residual + ELU -> out fp32 [N,64]
__global__ __launch_bounds__(256) void csr_agg_final(
    const int* __restrict__ rowptr, const int* __restrict__ col,
    const float* __restrict__ as_, const float* __restrict__ ad_,
    const unsigned short* __restrict__ hlin, const float* __restrict__ ident,
    const float* __restrict__ bias2, const float* __restrict__ g2,
    const float* __restrict__ b2, float* __restrict__ out) {
  const int n = blockIdx.x;
  const int tid = threadIdx.x;
  const int hh = tid >> 6, lane = tid & 63;
  const int sub = lane >> 3, cg = lane & 7;
  const unsigned short* hbase = hlin + hh * 64 + cg * 8;
  const float adv = ad_[n * 4 + hh];
  const int beg = rowptr[n], end = rowptr[n + 1];
  float acc[8] = {};
  float wsum = 0.f;
  for (int off = beg; off < end; off += 64) {
    const int len = min(64, end - off);
    int s_l = 0;
    float w_l = 0.f;
    if (lane < len) {
      s_l = col[off + lane];
      float v = as_[s_l * 4 + hh] + adv;
      v = v > 0.f ? v : NEG_SLOPE * v;
      w_l = expf(v);
    }
    wsum += w_l;
    for (int j = 0; j < len; j += 8) {
      const int s = __shfl(s_l, j + sub);
      const float w = __shfl(w_l, j + sub);
      const short8 hv = *(const short8*)(hbase + (size_t)s * HC);
#pragma unroll
      for (int t = 0; t < 8; ++t) acc[t] += w * bf2f((unsigned short)hv[t]);
    }
  }
#pragma unroll
  for (int off = 32; off > 0; off >>= 1) wsum += __shfl_xor(wsum, off);
#pragma unroll
  for (int t = 0; t < 8; ++t) {
    acc[t] += __shfl_xor(acc[t], 8);
    acc[t] += __shfl_xor(acc[t], 16);
    acc[t] += __shfl_xor(acc[t], 32);
  }
  __shared__ float sm[4][64];
  if (sub == 0) {
    const float inv = 1.0f / wsum;
#pragma unroll
    for (int t = 0; t < 8; ++t) sm[hh][cg * 8 + t] = acc[t] * inv;
  }
  __syncthreads();
  if (tid < 64) {
    float v = 0.25f * (sm[0][tid] + sm[1][tid] + sm[2][tid] + sm[3][tid]) + bias2[tid];
    float s1 = v, s2 = v * v;
#pragma unroll
    for (int off = 32; off > 0; off >>= 1) {
      s1 += __shfl_down(s1, off);
      s2 += __shfl_down(s2, off);
    }
    s1 = __shfl(s1, 0);
    s2 = __shfl(s2, 0);
    const float mu = s1 * (1.0f / 64.0f);
    const float var = s2 * (1.0f / 64.0f) - mu * mu;
    float y = (v - mu) * rsqrtf(var + LN_EPS) * g2[tid] + b2[tid];
    y += ident[(size_t)n * 64 + tid];
    out[(size_t)n * 64 + tid] = y > 0.f ? y : expm1f(y);
  }
}

extern "C" void kernel_launch(void* const* d_in, const int* in_sizes, int n_in,
                              void* d_out, int out_size, void* d_ws, size_t ws_size,
                              hipStream_t stream) {
  const float* x        = (const float*)d_in[0];
  const int*   ei       = (const int*)d_in[1];
  const float* W1       = (const float*)d_in[2];
  const float* att_src1 = (const float*)d_in[3];
  const float* att_dst1 = (const float*)d_in[4];
  const float* bias1    = (const float*)d_in[5];
  const float* g1       = (const float*)d_in[6];
  const float* b1       = (const float*)d_in[7];
  const float* W2       = (const float*)d_in[8];
  const float* att_src2 = (const float*)d_in[9];
  const float* att_dst2 = (const float*)d_in[10];
  const float* bias2    = (const float*)d_in[11];
  const float* g2       = (const float*)d_in[12];
  const float* b2       = (const float*)d_in[13];
  const float* Wres     = (const float*)d_in[14];
  const float* bres     = (const float*)d_in[15];

  const int N = in_sizes[0] / 128;   // 50000
  const int E = in_sizes[1] / 2;     // 800000
  const int IN = 128;
  const int Etot = E + N;

  const int* srcs = ei;
  const int* dsts = ei + E;

  // workspace layout (16B-aligned segments)
  char* p = (char*)d_ws;
  float* ident = (float*)p;            p += (size_t)N * 64 * 4;
  float* as_   = (float*)p;            p += (size_t)N * HH * 4;
  float* ad_   = (float*)p;            p += (size_t)N * HH * 4;
  int* rowptr  = (int*)p;              p += (size_t)(N + 4) * 4;
  int* deg     = (int*)p;              p += (size_t)N * 4;
  int* bsum    = (int*)p;              p += 256 * 4;
  int* col     = (int*)p;              p += (size_t)Etot * 4;
  p = (char*)(((uintptr_t)p + 15) & ~(uintptr_t)15);
  unsigned short* xb    = (unsigned short*)p; p += (size_t)N * IN * 2;
  unsigned short* hlinb = (unsigned short*)p; p += (size_t)N * HC * 2;
  unsigned short* h1b   = (unsigned short*)p; p += (size_t)N * HC * 2;
  unsigned short* wt1   = (unsigned short*)p; p += (size_t)IN * HC * 2;
  unsigned short* wt2   = (unsigned short*)p; p += (size_t)HC * HC * 2;
  unsigned short* wtres = (unsigned short*)p; p += (size_t)IN * 64 * 2;

  const int mblocks = (N + 63) / 64;
  const int nscan = (N + 255) / 256;
  dim3 blk(256);

  // ---- dtype prep ----
  cvt_bf16_x4<<<(N * IN / 4 + 255) / 256, blk, 0, stream>>>(x, xb, N * IN / 4);
  cvt_transpose<<<(IN * HC + 255) / 256, blk, 0, stream>>>(W1, wt1, IN, HC);
  cvt_transpose<<<(HC * HC + 255) / 256, blk, 0, stream>>>(W2, wt2, HC, HC);
  cvt_transpose<<<(IN * 64 + 255) / 256, blk, 0, stream>>>(Wres, wtres, IN, 64);

  // ---- CSR build ----
  deg_init<<<nscan, blk, 0, stream>>>(deg, N);
  deg_hist<<<(E + 255) / 256, blk, 0, stream>>>(dsts, deg, E);
  scan_block<<<nscan, blk, 0, stream>>>(deg, rowptr, bsum, N);
  scan_top<<<1, blk, 0, stream>>>(bsum, nscan);
  scan_add<<<nscan, blk, 0, stream>>>(bsum, rowptr, N);
  copy_cursor<<<nscan, blk, 0, stream>>>(rowptr, deg, N);
  csr_scatter<<<(Etot + 255) / 256, blk, 0, stream>>>(srcs, dsts, deg, col, E, N);

  // residual projection (fp32 out)
  gemm_bf16<float><<<dim3(mblocks, 1), blk, 0, stream>>>(xb, wtres, bres, ident, N, 64, IN);

  // ---- GAT layer 1 ----
  gemm_bf16<unsigned short><<<dim3(mblocks, 4), blk, 0, stream>>>(xb, wt1, nullptr, hlinb, N, HC, IN);
  alpha_kernel<<<N, blk, 0, stream>>>(hlinb, att_src1, att_dst1, as_, ad_);
  csr_agg_ln1<<<N, blk, 0, stream>>>(rowptr, col, as_, ad_, hlinb, bias1, g1, b1, h1b);

  // ---- GAT layer 2 ----
  gemm_bf16<unsigned short><<<dim3(mblocks, 4), blk, 0, stream>>>(h1b, wt2, nullptr, hlinb, N, HC, HC);
  alpha_kernel<<<N, blk, 0, stream>>>(hlinb, att_src2, att_dst2, as_, ad_);
  csr_agg_final<<<N, blk, 0, stream>>>(rowptr, col, as_, ad_, hlinb, ident,
                                       bias2, g2, b2, (float*)d_out);
}

// Round 5
// 481.103 us; speedup vs baseline: 4.4323x; 1.1301x over previous
//
#include <hip/hip_runtime.h>
#include <math.h>

// Problem constants: N=50000, IN=128, H=4, C=64, HC=256
#define HH 4
#define CC 64
#define HC 256

static constexpr float NEG_SLOPE = 0.2f;
static constexpr float LN_EPS = 1e-5f;

typedef __attribute__((ext_vector_type(8))) short short8;
typedef __attribute__((ext_vector_type(4))) float floatx4;

__device__ __forceinline__ float bf2f(unsigned short u) {
  return __uint_as_float(((unsigned int)u) << 16);
}
__device__ __forceinline__ unsigned short f2bf(float f) {
  unsigned int u = __float_as_uint(f);
  u = (u + 0x7fff + ((u >> 16) & 1)) >> 16;  // round-to-nearest-even
  return (unsigned short)u;
}
__device__ __forceinline__ void store_out(float* p, float v) { *p = v; }
__device__ __forceinline__ void store_out(unsigned short* p, float v) { *p = f2bf(v); }

// 8 bf16 (as uint4) * w -> acc[8]; 2 VALU per element (shift/and + fmac)
__device__ __forceinline__ void macc8(float* acc, uint4 h, float w) {
  acc[0] += w * __uint_as_float(h.x << 16);
  acc[1] += w * __uint_as_float(h.x & 0xffff0000u);
  acc[2] += w * __uint_as_float(h.y << 16);
  acc[3] += w * __uint_as_float(h.y & 0xffff0000u);
  acc[4] += w * __uint_as_float(h.z << 16);
  acc[5] += w * __uint_as_float(h.z & 0xffff0000u);
  acc[6] += w * __uint_as_float(h.w << 16);
  acc[7] += w * __uint_as_float(h.w & 0xffff0000u);
}

// ---------------- dtype prep ----------------
__global__ __launch_bounds__(256) void cvt_bf16_x4(
    const float* __restrict__ src, unsigned short* __restrict__ dst, int n4) {
  const int i = blockIdx.x * 256 + threadIdx.x;
  if (i < n4) {
    const float4 v = ((const float4*)src)[i];
    ushort4 o;
    o.x = f2bf(v.x); o.y = f2bf(v.y); o.z = f2bf(v.z); o.w = f2bf(v.w);
    ((ushort4*)dst)[i] = o;
  }
}

// all three weight transposes in one kernel.
// W1 [128,256]->wt1[256,128]; W2 [256,256]->wt2[256,256]; Wres [128,64]->wtres[64,128]
__global__ __launch_bounds__(256) void cvt_weights(
    const float* __restrict__ W1, const float* __restrict__ W2,
    const float* __restrict__ Wres,
    unsigned short* __restrict__ wt1, unsigned short* __restrict__ wt2,
    unsigned short* __restrict__ wtres) {
  const int idx = blockIdx.x * 256 + threadIdx.x;
  if (idx < 32768) {                       // W1: k*256+n
    const int k = idx >> 8, n = idx & 255;
    wt1[n * 128 + k] = f2bf(W1[idx]);
  } else if (idx < 98304) {                // W2
    const int i = idx - 32768;
    const int k = i >> 8, n = i & 255;
    wt2[n * 256 + k] = f2bf(W2[i]);
  } else if (idx < 106496) {               // Wres: k*64+n
    const int i = idx - 98304;
    const int k = i >> 6, n = i & 63;
    wtres[n * 128 + k] = f2bf(Wres[i]);
  }
}

// ---------------- bf16 MFMA GEMM + optional fused alpha epilogue ----------------
// A bf16 [M,K]; BT bf16 [Nc,K]. Tile 64x64, BK=32, 4 waves.
// When DO_ALPHA: Nc==256, each col-tile is one head (hh=col0>>6); computes
// as_[row*4+hh] = sum_c C[row,hh*64+c]*att_src[hh*64+c] (ditto ad_) in-register.
template <typename OutT, bool DO_ALPHA>
__global__ __launch_bounds__(256) void gemm_bf16(
    const unsigned short* __restrict__ A, const unsigned short* __restrict__ BT,
    const float* __restrict__ bias, OutT* __restrict__ C,
    const float* __restrict__ att_src, const float* __restrict__ att_dst,
    float* __restrict__ as_, float* __restrict__ ad_,
    int M, int Nc, int K) {
  __shared__ unsigned short As[64][40];
  __shared__ unsigned short Bs[64][40];
  const int tid = threadIdx.x;
  const int w = tid >> 6;
  const int lane = tid & 63;
  const int q = lane >> 4;
  const int mr = lane & 15;
  const int row0 = blockIdx.x * 64;
  const int col0 = blockIdx.y * 64;
  const int sr = tid >> 2;
  const int sk = (tid & 3) * 8;

  floatx4 acc[4] = {};

  for (int k0 = 0; k0 < K; k0 += 32) {
    const int arow = row0 + sr;
    short8 av8 = {};
    if (arow < M) av8 = *(const short8*)(A + (size_t)arow * K + k0 + sk);
    *(short8*)(&As[sr][sk]) = av8;
    *(short8*)(&Bs[sr][sk]) = *(const short8*)(BT + (size_t)(col0 + sr) * K + k0 + sk);
    __syncthreads();
    const short8 af = *(const short8*)(&As[w * 16 + mr][q * 8]);
#pragma unroll
    for (int ct = 0; ct < 4; ++ct) {
      const short8 bf = *(const short8*)(&Bs[ct * 16 + mr][q * 8]);
      acc[ct] = __builtin_amdgcn_mfma_f32_16x16x32_bf16(af, bf, acc[ct], 0, 0, 0);
    }
    __syncthreads();
  }
  // C-write. C/D layout: col=lane&15, row=q*4+reg.
#pragma unroll
  for (int ct = 0; ct < 4; ++ct) {
#pragma unroll
    for (int r = 0; r < 4; ++r) {
      const int row = row0 + w * 16 + q * 4 + r;
      if (row < M) {
        const int cc = col0 + ct * 16 + mr;
        float v = acc[ct][r];
        if (bias) v += bias[cc];
        store_out(C + (size_t)row * Nc + cc, v);
      }
    }
  }
  if (DO_ALPHA) {
    const int hh = col0 >> 6;
    float pa[4] = {}, pb[4] = {};
#pragma unroll
    for (int ct = 0; ct < 4; ++ct) {
      const float a_s = att_src[col0 + ct * 16 + mr];
      const float a_d = att_dst[col0 + ct * 16 + mr];
#pragma unroll
      for (int r = 0; r < 4; ++r) {
        pa[r] += acc[ct][r] * a_s;
        pb[r] += acc[ct][r] * a_d;
      }
    }
#pragma unroll
    for (int off = 1; off < 16; off <<= 1) {
#pragma unroll
      for (int r = 0; r < 4; ++r) {
        pa[r] += __shfl_xor(pa[r], off);
        pb[r] += __shfl_xor(pb[r], off);
      }
    }
    if (mr == 0) {
#pragma unroll
      for (int r = 0; r < 4; ++r) {
        const int row = row0 + w * 16 + q * 4 + r;
        if (row < M) {
          as_[row * 4 + hh] = pa[r];
          ad_[row * 4 + hh] = pb[r];
        }
      }
    }
  }
}

// ================= CSR construction =================
__global__ __launch_bounds__(256) void deg_hist(
    const int* __restrict__ dsts, int* __restrict__ deg, int E) {
  const int e = blockIdx.x * 256 + threadIdx.x;
  if (e < E) atomicAdd(&deg[dsts[e]], 1);
}

// deg counts edges only; +1 here for the self-loop.
__global__ __launch_bounds__(256) void scan_block(
    const int* __restrict__ deg, int* __restrict__ rowptr, int* __restrict__ bsum, int N) {
  const int b = blockIdx.x, t = threadIdx.x, g = b * 256 + t;
  const int lane = t & 63, w = t >> 6;
  int x = (g < N) ? deg[g] + 1 : 0;
#pragma unroll
  for (int off = 1; off < 64; off <<= 1) {
    const int y = __shfl_up(x, off);
    if (lane >= off) x += y;
  }
  __shared__ int wsum[4];
  if (lane == 63) wsum[w] = x;
  __syncthreads();
  int add = 0;
  for (int i = 0; i < w; ++i) add += wsum[i];
  x += add;
  if (g < N) rowptr[g + 1] = x;
  if (t == 255) bsum[b] = x;
}

__global__ __launch_bounds__(256) void scan_top(int* __restrict__ bsum, int nb) {
  const int t = threadIdx.x;
  const int lane = t & 63, w = t >> 6;
  const int v = (t < nb) ? bsum[t] : 0;
  int x = v;
#pragma unroll
  for (int off = 1; off < 64; off <<= 1) {
    const int y = __shfl_up(x, off);
    if (lane >= off) x += y;
  }
  __shared__ int wsum[4];
  if (lane == 63) wsum[w] = x;
  __syncthreads();
  int add = 0;
  for (int i = 0; i < w; ++i) add += wsum[i];
  x += add;
  if (t < nb) bsum[t] = x - v;  // exclusive
}

// finalize rowptr and produce cursor[g] = rowptr[g] (= rowptr[g+1] - deg[g] - 1)
__global__ __launch_bounds__(256) void scan_add(
    const int* __restrict__ bsum, int* __restrict__ rowptr,
    int* __restrict__ deg_to_cursor, int N) {
  const int g = blockIdx.x * 256 + threadIdx.x;
  if (g == 0) rowptr[0] = 0;
  if (g < N) {
    const int v = rowptr[g + 1] + bsum[blockIdx.x];
    rowptr[g + 1] = v;
    deg_to_cursor[g] = v - deg_to_cursor[g] - 1;  // exclusive start
  }
}

__global__ __launch_bounds__(256) void csr_scatter(
    const int* __restrict__ srcs, const int* __restrict__ dsts,
    int* __restrict__ cursor, int* __restrict__ col, int E, int N) {
  const int e = blockIdx.x * 256 + threadIdx.x;
  if (e >= E + N) return;
  int s, d;
  if (e < E) { s = srcs[e]; d = dsts[e]; }
  else       { s = e - E; d = s; }
  const int pos = atomicAdd(&cursor[d], 1);
  col[pos] = s;
}

// ================= fused CSR aggregation (vectorized + 2x unrolled gather) =================
__global__ __launch_bounds__(256) void csr_agg_ln1(
    const int* __restrict__ rowptr, const int* __restrict__ col,
    const float* __restrict__ as_, const float* __restrict__ ad_,
    const unsigned short* __restrict__ hlin, const float* __restrict__ bias1,
    const float* __restrict__ g1, const float* __restrict__ b1,
    unsigned short* __restrict__ h1) {
  const int n = blockIdx.x;
  const int tid = threadIdx.x;
  const int hh = tid >> 6, lane = tid & 63;
  const int sub = lane >> 3, cg = lane & 7;
  const uint4* hb = (const uint4*)(hlin + hh * 64 + cg * 8);  // row stride = 32 uint4
  const float adv = ad_[n * 4 + hh];
  const int beg = rowptr[n], end = rowptr[n + 1];
  float acc[8] = {};
  float wsum = 0.f;
  for (int off = beg; off < end; off += 64) {
    const int len = min(64, end - off);
    int s_l = 0;
    float w_l = 0.f;
    if (lane < len) {
      s_l = col[off + lane];
      float v = as_[s_l * 4 + hh] + adv;
      v = v > 0.f ? v : NEG_SLOPE * v;
      w_l = expf(v);
    }
    wsum += w_l;
    int j = 0;
    for (; j + 16 <= len; j += 16) {
      const int sA = __shfl(s_l, j + sub);
      const int sB = __shfl(s_l, j + 8 + sub);
      const float wA = __shfl(w_l, j + sub);
      const float wB = __shfl(w_l, j + 8 + sub);
      const uint4 hA = hb[(size_t)sA * 32];
      const uint4 hB = hb[(size_t)sB * 32];
      macc8(acc, hA, wA);
      macc8(acc, hB, wB);
    }
    for (; j < len; j += 8) {
      const int s = __shfl(s_l, j + sub);
      const float w = __shfl(w_l, j + sub);
      macc8(acc, hb[(size_t)s * 32], w);
    }
  }
#pragma unroll
  for (int off = 32; off > 0; off >>= 1) wsum += __shfl_xor(wsum, off);
#pragma unroll
  for (int t = 0; t < 8; ++t) {
    acc[t] += __shfl_xor(acc[t], 8);
    acc[t] += __shfl_xor(acc[t], 16);
    acc[t] += __shfl_xor(acc[t], 32);
  }
  __shared__ float vals[HC];
  if (sub == 0) {
    const float inv = 1.0f / wsum;
#pragma unroll
    for (int t = 0; t < 8; ++t) vals[hh * 64 + cg * 8 + t] = acc[t] * inv;
  }
  __syncthreads();
  const float val = vals[tid] + bias1[tid];
  float s1 = val, s2 = val * val;
#pragma unroll
  for (int off = 32; off > 0; off >>= 1) {
    s1 += __shfl_down(s1, off);
    s2 += __shfl_down(s2, off);
  }
  __shared__ float ws1[4], ws2[4];
  if (lane == 0) { ws1[hh] = s1; ws2[hh] = s2; }
  __syncthreads();
  const float tot1 = ws1[0] + ws1[1] + ws1[2] + ws1[3];
  const float tot2 = ws2[0] + ws2[1] + ws2[2] + ws2[3];
  const float mu = tot1 * (1.0f / HC);
  const float var = tot2 * (1.0f / HC) - mu * mu;
  float y = (val - mu) * rsqrtf(var + LN_EPS) * g1[tid] + b1[tid];
  y = y > 0.f ? y : expm1f(y);
  h1[(size_t)n * HC + tid] = f2bf(y);
}

__global__ __launch_bounds__(256) void csr_agg_final(
    const int* __restrict__ rowptr, const int* __restrict__ col,
    const float* __restrict__ as_, const float* __restrict__ ad_,
    const unsigned short* __restrict__ hlin, const float* __restrict__ ident,
    const float* __restrict__ bias2, const float* __restrict__ g2,
    const float* __restrict__ b2, float* __restrict__ out) {
  const int n = blockIdx.x;
  const int tid = threadIdx.x;
  const int hh = tid >> 6, lane = tid & 63;
  const int sub = lane >> 3, cg = lane & 7;
  const uint4* hb = (const uint4*)(hlin + hh * 64 + cg * 8);
  const float adv = ad_[n * 4 + hh];
  const int beg = rowptr[n], end = rowptr[n + 1];
  float acc[8] = {};
  float wsum = 0.f;
  for (int off = beg; off < end; off += 64) {
    const int len = min(64, end - off);
    int s_l = 0;
    float w_l = 0.f;
    if (lane < len) {
      s_l = col[off + lane];
      float v = as_[s_l * 4 + hh] + adv;
      v = v > 0.f ? v : NEG_SLOPE * v;
      w_l = expf(v);
    }
    wsum += w_l;
    int j = 0;
    for (; j + 16 <= len; j += 16) {
      const int sA = __shfl(s_l, j + sub);
      const int sB = __shfl(s_l, j + 8 + sub);
      const float wA = __shfl(w_l, j + sub);
      const float wB = __shfl(w_l, j + 8 + sub);
      const uint4 hA = hb[(size_t)sA * 32];
      const uint4 hB = hb[(size_t)sB * 32];
      macc8(acc, hA, wA);
      macc8(acc, hB, wB);
    }
    for (; j < len; j += 8) {
      const int s = __shfl(s_l, j + sub);
      const float w = __shfl(w_l, j + sub);
      macc8(acc, hb[(size_t)s * 32], w);
    }
  }
#pragma unroll
  for (int off = 32; off > 0; off >>= 1) wsum += __shfl_xor(wsum, off);
#pragma unroll
  for (int t = 0; t < 8; ++t) {
    acc[t] += __shfl_xor(acc[t], 8);
    acc[t] += __shfl_xor(acc[t], 16);
    acc[t] += __shfl_xor(acc[t], 32);
  }
  __shared__ float sm[4][64];
  if (sub == 0) {
    const float inv = 1.0f / wsum;
#pragma unroll
    for (int t = 0; t < 8; ++t) sm[hh][cg * 8 + t] = acc[t] * inv;
  }
  __syncthreads();
  if (tid < 64) {
    float v = 0.25f * (sm[0][tid] + sm[1][tid] + sm[2][tid] + sm[3][tid]) + bias2[tid];
    float s1 = v, s2 = v * v;
#pragma unroll
    for (int off = 32; off > 0; off >>= 1) {
      s1 += __shfl_down(s1, off);
      s2 += __shfl_down(s2, off);
    }
    s1 = __shfl(s1, 0);
    s2 = __shfl(s2, 0);
    const float mu = s1 * (1.0f / 64.0f);
    const float var = s2 * (1.0f / 64.0f) - mu * mu;
    float y = (v - mu) * rsqrtf(var + LN_EPS) * g2[tid] + b2[tid];
    y += ident[(size_t)n * 64 + tid];
    out[(size_t)n * 64 + tid] = y > 0.f ? y : expm1f(y);
  }
}

extern "C" void kernel_launch(void* const* d_in, const int* in_sizes, int n_in,
                              void* d_out, int out_size, void* d_ws, size_t ws_size,
                              hipStream_t stream) {
  const float* x        = (const float*)d_in[0];
  const int*   ei       = (const int*)d_in[1];
  const float* W1       = (const float*)d_in[2];
  const float* att_src1 = (const float*)d_in[3];
  const float* att_dst1 = (const float*)d_in[4];
  const float* bias1    = (const float*)d_in[5];
  const float* g1       = (const float*)d_in[6];
  const float* b1       = (const float*)d_in[7];
  const float* W2       = (const float*)d_in[8];
  const float* att_src2 = (const float*)d_in[9];
  const float* att_dst2 = (const float*)d_in[10];
  const float* bias2    = (const float*)d_in[11];
  const float* g2       = (const float*)d_in[12];
  const float* b2       = (const float*)d_in[13];
  const float* Wres     = (const float*)d_in[14];
  const float* bres     = (const float*)d_in[15];

  const int N = in_sizes[0] / 128;   // 50000
  const int E = in_sizes[1] / 2;     // 800000
  const int IN = 128;
  const int Etot = E + N;

  const int* srcs = ei;
  const int* dsts = ei + E;

  // workspace layout (16B-aligned segments)
  char* p = (char*)d_ws;
  float* ident = (float*)p;            p += (size_t)N * 64 * 4;
  float* as_   = (float*)p;            p += (size_t)N * HH * 4;
  float* ad_   = (float*)p;            p += (size_t)N * HH * 4;
  int* rowptr  = (int*)p;              p += (size_t)(N + 4) * 4;
  int* deg     = (int*)p;              p += (size_t)N * 4;   // degree -> cursor
  int* bsum    = (int*)p;              p += 256 * 4;
  int* col     = (int*)p;              p += (size_t)Etot * 4;
  p = (char*)(((uintptr_t)p + 15) & ~(uintptr_t)15);
  unsigned short* xb    = (unsigned short*)p; p += (size_t)N * IN * 2;
  unsigned short* hlinb = (unsigned short*)p; p += (size_t)N * HC * 2;
  unsigned short* h1b   = (unsigned short*)p; p += (size_t)N * HC * 2;
  unsigned short* wt1   = (unsigned short*)p; p += (size_t)IN * HC * 2;
  unsigned short* wt2   = (unsigned short*)p; p += (size_t)HC * HC * 2;
  unsigned short* wtres = (unsigned short*)p; p += (size_t)IN * 64 * 2;

  const int mblocks = (N + 63) / 64;
  const int nscan = (N + 255) / 256;
  dim3 blk(256);

  // ---- dtype prep ----
  cvt_bf16_x4<<<(N * IN / 4 + 255) / 256, blk, 0, stream>>>(x, xb, N * IN / 4);
  cvt_weights<<<(106496 + 255) / 256, blk, 0, stream>>>(W1, W2, Wres, wt1, wt2, wtres);

  // ---- CSR build ----
  hipMemsetAsync(deg, 0, (size_t)N * sizeof(int), stream);
  deg_hist<<<(E + 255) / 256, blk, 0, stream>>>(dsts, deg, E);
  scan_block<<<nscan, blk, 0, stream>>>(deg, rowptr, bsum, N);
  scan_top<<<1, blk, 0, stream>>>(bsum, nscan);
  scan_add<<<nscan, blk, 0, stream>>>(bsum, rowptr, deg, N);
  csr_scatter<<<(Etot + 255) / 256, blk, 0, stream>>>(srcs, dsts, deg, col, E, N);

  // residual projection (fp32 out, no alpha)
  gemm_bf16<float, false><<<dim3(mblocks, 1), blk, 0, stream>>>(
      xb, wtres, bres, ident, nullptr, nullptr, nullptr, nullptr, N, 64, IN);

  // ---- GAT layer 1 ----
  gemm_bf16<unsigned short, true><<<dim3(mblocks, 4), blk, 0, stream>>>(
      xb, wt1, nullptr, hlinb, att_src1, att_dst1, as_, ad_, N, HC, IN);
  csr_agg_ln1<<<N, blk, 0, stream>>>(rowptr, col, as_, ad_, hlinb, bias1, g1, b1, h1b);

  // ---- GAT layer 2 ----
  gemm_bf16<unsigned short, true><<<dim3(mblocks, 4), blk, 0, stream>>>(
      h1b, wt2, nullptr, hlinb, att_src2, att_dst2, as_, ad_, N, HC, HC);
  csr_agg_final<<<N, blk, 0, stream>>>(rowptr, col, as_, ad_, hlinb, ident,
                                       bias2, g2, b2, (float*)d_out);
}